// Round 1
// 105.898 us; speedup vs baseline: 1.0079x; 1.0079x over previous
//
#include <hip/hip_runtime.h>
#include <hip/hip_bf16.h>

typedef _Float16 h2 __attribute__((ext_vector_type(2)));
typedef float f32x2 __attribute__((ext_vector_type(2)));

constexpr int kB = 4, kN = 256, kC = 256, kH = 8, kF = 64, kHF = 512;
constexpr int kIPB = 4;   // attention rows (i) per block

union H2U { h2 h; unsigned int u; };

// DPP butterfly add: x + x[src-lane(CTRL)].  All-lane-valid patterns only.
// 0xB1 = quad_perm xor1, 0x4E = quad_perm xor2,
// 0x141 = row_half_mirror (== xor4 once quads are uniform),
// 0x128 = row_ror:8 (== xor8 exactly).
#define DPP_ADD(x, CTRL) \
    ((x) + __int_as_float(__builtin_amdgcn_update_dpp( \
        0, __float_as_int(x), (CTRL), 0xF, 0xF, true)))

// ---------------------------------------------------------------------------
// Phase A: g = x @ W  (fp32 in, f16 out to ws). W selected by blockIdx.y.
// Block: 256 threads, 4 rows x 512 cols (thread = 4 rows x 2 cols).
// Grid: (B*N/4, 2) = (256, 2) -> 512 blocks, 2 blocks/CU.
// W loads double-buffered 2 chunks deep (8 k's) to cover L2 latency at
// 2 waves/SIMD.
// ---------------------------------------------------------------------------
__global__ __launch_bounds__(256) void gat_gemm_kernel(
    const float* __restrict__ x,
    const float* __restrict__ Wl,
    const float* __restrict__ Wr,
    unsigned int* __restrict__ gl,    // f16 pairs
    unsigned int* __restrict__ gr)
{
    __shared__ float xs[4][kC];   // 4 KiB
    const int rowBase = blockIdx.x * 4;
    const float* Wm = (blockIdx.y == 0) ? Wl : Wr;
    unsigned int* gout = (blockIdx.y == 0) ? gl : gr;

    const int tid = threadIdx.x;

    // Stage 4 rows of x into LDS (256 thr x 4 floats = 1024).
    {
        const int r = tid >> 6;
        const int kc = (tid & 63) * 4;
        *(float4*)&xs[r][kc] = *(const float4*)(x + (rowBase + r) * kC + kc);
    }
    __syncthreads();

    const int c0 = tid * 2;           // two adjacent output cols
    float acc[4][2];
#pragma unroll
    for (int r = 0; r < 4; ++r) { acc[r][0] = 0.f; acc[r][1] = 0.f; }

    // depth-2 register double buffer of W chunks (4 k's per chunk)
    float2 w0[4], w1[4];
#pragma unroll
    for (int kk = 0; kk < 4; ++kk) {
        w0[kk] = *(const float2*)(Wm + kk * kHF + c0);
        w1[kk] = *(const float2*)(Wm + (4 + kk) * kHF + c0);
    }

    for (int k = 0; k < kC; k += 4) {
        const int kn = (k + 8) & (kC - 1);   // wraps at tail; harmless reload
        float2 wn[4];
#pragma unroll
        for (int kk = 0; kk < 4; ++kk)
            wn[kk] = *(const float2*)(Wm + (kn + kk) * kHF + c0);
#pragma unroll
        for (int r = 0; r < 4; ++r) {
            float4 xv = *(const float4*)&xs[r][k];
            acc[r][0] = fmaf(xv.x, w0[0].x, acc[r][0]);
            acc[r][1] = fmaf(xv.x, w0[0].y, acc[r][1]);
            acc[r][0] = fmaf(xv.y, w0[1].x, acc[r][0]);
            acc[r][1] = fmaf(xv.y, w0[1].y, acc[r][1]);
            acc[r][0] = fmaf(xv.z, w0[2].x, acc[r][0]);
            acc[r][1] = fmaf(xv.z, w0[2].y, acc[r][1]);
            acc[r][0] = fmaf(xv.w, w0[3].x, acc[r][0]);
            acc[r][1] = fmaf(xv.w, w0[3].y, acc[r][1]);
        }
#pragma unroll
        for (int kk = 0; kk < 4; ++kk) { w0[kk] = w1[kk]; w1[kk] = wn[kk]; }
    }

#pragma unroll
    for (int r = 0; r < 4; ++r) {
        H2U p; p.h = (h2){(_Float16)acc[r][0], (_Float16)acc[r][1]};
        gout[((rowBase + r) * kHF + c0) >> 1] = p.u;
    }
}

// ---------------------------------------------------------------------------
// Phase B: fused leaky-dot / head-softmax / aggregation, f16 math.
// Block = 1024 threads (16 waves) covering 4 consecutive (b,i) rows.
// lane = h*8+fg; lane owns f = fg*8..+7. Wave wv handles j = wv, wv+16, ...
// v2: DPP butterflies replace 4 of 6 ds_bpermute shuffles per (ii,j);
// adj prefetched one tile ahead; packed-f32 accumulation.
// ---------------------------------------------------------------------------
__global__ __launch_bounds__(1024, 4) void gat_attn_kernel(
    const unsigned int* __restrict__ gl,   // f16 pairs
    const unsigned int* __restrict__ gr,
    const float* __restrict__ attn_w,
    const int* __restrict__ adj,
    float* __restrict__ out)
{
    __shared__ float red[8 * kIPB * kHF];  // 64 KiB

    const int bi0 = blockIdx.x * kIPB;     // first row (b*N + i)
    const int b = bi0 >> 8;
    const int i0 = bi0 & 255;
    const int tid = threadIdx.x;
    const int wv = tid >> 6;               // 0..15
    const int lane = tid & 63;
    const int h = lane >> 3;
    const int fg = lane & 7;
    const int fbase = fg * 8;

    // Preload g_r[b, i0+ii, h, fbase..+7] as h2 and attn_w as h2.
    h2 gri[kIPB][4];
#pragma unroll
    for (int ii = 0; ii < kIPB; ++ii) {
        uint4 pk = *(const uint4*)(gr +
            (((size_t)(bi0 + ii) * kHF + h * kF + fbase) >> 1));
        H2U a0, a1, a2, a3;
        a0.u = pk.x; a1.u = pk.y; a2.u = pk.z; a3.u = pk.w;
        gri[ii][0] = a0.h; gri[ii][1] = a1.h; gri[ii][2] = a2.h; gri[ii][3] = a3.h;
    }
    h2 w2[4];
    {
        float4 wa = *(const float4*)(attn_w + fbase);
        float4 wb = *(const float4*)(attn_w + fbase + 4);
        w2[0] = (h2){(_Float16)wa.x, (_Float16)wa.y};
        w2[1] = (h2){(_Float16)wa.z, (_Float16)wa.w};
        w2[2] = (h2){(_Float16)wb.x, (_Float16)wb.y};
        w2[3] = (h2){(_Float16)wb.z, (_Float16)wb.w};
    }

    f32x2 acc[kIPB][4];
#pragma unroll
    for (int ii = 0; ii < kIPB; ++ii)
#pragma unroll
        for (int q = 0; q < 4; ++q) acc[ii][q] = (f32x2){0.f, 0.f};

    const h2 c02 = (h2){(_Float16)0.2f, (_Float16)0.2f};
    const size_t gcolbase = (size_t)(b * kN) * kHF + h * kF + fbase;
    const int adjbase = i0 * kN * kH + h;

    // software-pipelined loads: g tiles + adj masks one j ahead
    size_t off = (gcolbase + (size_t)wv * kHF) >> 1;
    uint4 ga = *(const uint4*)(gl + off);
    uint4 gb = *(const uint4*)(gr + off);
    int am[kIPB];
#pragma unroll
    for (int ii = 0; ii < kIPB; ++ii)
        am[ii] = adj[adjbase + (ii * kN + wv) * kH];

    for (int j = wv; j < kN; j += 16) {
        // prefetch next tile (wrapped index: always a valid address)
        const int jn = (j + 16) & 255;
        const size_t offn = (gcolbase + (size_t)jn * kHF) >> 1;
        uint4 ga_n = *(const uint4*)(gl + offn);
        uint4 gb_n = *(const uint4*)(gr + offn);
        int am_n[kIPB];
#pragma unroll
        for (int ii = 0; ii < kIPB; ++ii)
            am_n[ii] = adj[adjbase + (ii * kN + jn) * kH];

        h2 gl2[4], gr2[4];
        { H2U t; t.u = ga.x; gl2[0] = t.h; t.u = ga.y; gl2[1] = t.h;
                 t.u = ga.z; gl2[2] = t.h; t.u = ga.w; gl2[3] = t.h;
                 t.u = gb.x; gr2[0] = t.h; t.u = gb.y; gr2[1] = t.h;
                 t.u = gb.z; gr2[2] = t.h; t.u = gb.w; gr2[3] = t.h; }

        // g_r[j] to f32 once, shared by the 4 i's
        f32x2 grf[4];
#pragma unroll
        for (int q = 0; q < 4; ++q)
            grf[q] = (f32x2){(float)gr2[q].x, (float)gr2[q].y};

#pragma unroll
        for (int ii = 0; ii < kIPB; ++ii) {
            float e = 0.f;
#pragma unroll
            for (int q = 0; q < 4; ++q) {
                h2 s = gri[ii][q] + gl2[q];
                h2 u = __builtin_elementwise_max(s, c02 * s);  // leaky 0.2
                e = __builtin_amdgcn_fdot2(u, w2[q], e, false);
            }
            // reduce over fg (lane bits 0..2) — pure DPP, no LDS
            e = DPP_ADD(e, 0xB1);    // xor1
            e = DPP_ADD(e, 0x4E);    // xor2
            e = DPP_ADD(e, 0x141);   // xor4 (half-mirror, quads uniform)

            float ex = am[ii] ? __expf(e) : 0.f;

            // softmax denominator over h (lane bits 3..5)
            float den = DPP_ADD(ex, 0x128);   // xor8 via row_ror:8
            den += __shfl_xor(den, 16);
            den += __shfl_xor(den, 32);
            const float av = ex * __builtin_amdgcn_rcpf(den);
            const f32x2 a2 = {av, av};
#pragma unroll
            for (int q = 0; q < 4; ++q)
                acc[ii][q] += a2 * grf[q];     // v_pk_fma_f32
        }

        ga = ga_n; gb = gb_n;
#pragma unroll
        for (int ii = 0; ii < kIPB; ++ii) am[ii] = am_n[ii];
    }

    // -------- two-stage cross-wave reduction (16 -> 8 -> 1) --------
    if (wv >= 8) {
#pragma unroll
        for (int ii = 0; ii < kIPB; ++ii) {
            const float* ap = (const float*)acc[ii];
            float* rp = &red[((wv - 8) * kIPB + ii) * kHF + lane * 8];
#pragma unroll
            for (int q = 0; q < 8; ++q) rp[q] = ap[q];
        }
    }
    __syncthreads();
    if (wv < 8) {
#pragma unroll
        for (int ii = 0; ii < kIPB; ++ii) {
            const float* ap = (const float*)acc[ii];
            float* rp = &red[(wv * kIPB + ii) * kHF + lane * 8];
#pragma unroll
            for (int q = 0; q < 8; ++q) rp[q] += ap[q];
        }
    }
    __syncthreads();

    // final: 2048 outputs, 1024 threads -> 2 per thread
#pragma unroll
    for (int t = tid; t < kIPB * kHF; t += 1024) {
        const int ii = t >> 9;
        const int c  = t & 511;
        float s = 0.f;
#pragma unroll
        for (int w8 = 0; w8 < 8; ++w8)
            s += red[(w8 * kIPB + ii) * kHF + c];
        out[(size_t)(bi0 + ii) * kHF + c] = s;
    }
}

// ---------------------------------------------------------------------------
extern "C" void kernel_launch(void* const* d_in, const int* in_sizes, int n_in,
                              void* d_out, int out_size, void* d_ws, size_t ws_size,
                              hipStream_t stream) {
    const float* x  = (const float*)d_in[0];
    const float* Wl = (const float*)d_in[1];
    const float* Wr = (const float*)d_in[2];
    const float* aw = (const float*)d_in[3];
    const int* adj  = (const int*)d_in[4];

    unsigned int* gl = (unsigned int*)d_ws;                    // [B*N*HF/2]
    unsigned int* gr = gl + (size_t)kB * kN * kHF / 2;

    dim3 g1(kB * kN / 4, 2);
    gat_gemm_kernel<<<g1, 256, 0, stream>>>(x, Wl, Wr, gl, gr);

    gat_attn_kernel<<<kB * kN / kIPB, 1024, 0, stream>>>(
        gl, gr, aw, adj, (float*)d_out);
}